// Round 10
// baseline (19824.132 us; speedup 1.0000x reference)
//
#include <hip/hip_runtime.h>
#include <hip/hip_bf16.h>

#define S_LEN 8192
#define LC 16
#define CE 64
#define CH 64
#define WE 128
#define NTAGS 50
#define WIN 32

using bf16 = __hip_bfloat16;
typedef unsigned int u32;
typedef unsigned long long u64;
typedef __fp16 h2 __attribute__((ext_vector_type(2)));   // matches pkrtz/fdot2
union h2u { h2 h; u32 u; };

__device__ __forceinline__ float bfbits2f(unsigned short u) {
    union { unsigned int i; float f; } v; v.i = ((unsigned int)u) << 16; return v.f;
}
__device__ __forceinline__ float sigm(float x) {
    return __builtin_amdgcn_rcpf(1.0f + __expf(-x));
}
__device__ __forceinline__ float tanh_fast(float x) {
    return 1.0f - 2.0f * __builtin_amdgcn_rcpf(__expf(2.0f * x) + 1.0f);
}
__device__ __forceinline__ float dot2f(h2 a, h2 b, float c) {
#if __has_builtin(__builtin_amdgcn_fdot2)
    return __builtin_amdgcn_fdot2(a, b, c, false);
#else
    return fmaf((float)a.x, (float)b.x, fmaf((float)a.y, (float)b.y, c));
#endif
}

// dtype-generic accessors ----------------------------------------------------
template <bool BF>
__device__ __forceinline__ float ld1(const void* p, size_t i) {
    if constexpr (BF) return bfbits2f(((const unsigned short*)p)[i]);
    else              return ((const float*)p)[i];
}
template <bool BF>
__device__ __forceinline__ float4 ld4(const void* p, size_t i) {  // elems i..i+3
    if constexpr (BF) {
        const ushort4 s = *reinterpret_cast<const ushort4*>((const unsigned short*)p + i);
        return make_float4(bfbits2f(s.x), bfbits2f(s.y), bfbits2f(s.z), bfbits2f(s.w));
    } else {
        return *reinterpret_cast<const float4*>((const float*)p + i);
    }
}
template <bool BF>
__device__ __forceinline__ void st1(void* p, size_t i, float v) {
    if constexpr (BF) ((bf16*)p)[i] = __float2bfloat16(v);
    else              ((float*)p)[i] = v;
}

// ---------------------------------------------------------------------------
// Detector: classify float-tensor dtype from char_emb's first 256 ushorts.
// ---------------------------------------------------------------------------
__global__ void kdetect(const void* emb, u32* flag) {
    const int j = threadIdx.x;           // 64 lanes
    int s = 0;
    #pragma unroll
    for (int k = 0; k < 4; ++k) {
        const unsigned short u = ((const unsigned short*)emb)[j * 4 + k];
        const int e = (u >> 7) & 0xFF;
        s += (e >= 100 && e <= 133) ? 1 : 0;
    }
    #pragma unroll
    for (int off = 32; off >= 1; off >>= 1) s += __shfl_xor(s, off, 64);
    if (j == 0) *flag = (s >= 200) ? 1u : 0u;
}

// ---------------------------------------------------------------------------
// Kernel A: char LSTM. 8 words/block, 256 threads (thread j = gate row j).
// ---------------------------------------------------------------------------
template <bool BF>
__global__ __launch_bounds__(256, 2) void kchar(
        const u32* __restrict__ dtf,
        const int* __restrict__ char_idxs, const int* __restrict__ char_lens,
        const void* __restrict__ char_emb,
        const void* __restrict__ Wih, const void* __restrict__ Whh,
        const void* __restrict__ bih, const void* __restrict__ bhh,
        float* __restrict__ cfeat) {
    if ((*dtf != 0u) != BF) return;
    const int j = threadIdx.x;
    const int w0 = blockIdx.x * 8;

    __shared__ __align__(16) float emb_lds[128 * CE];     // 32 KB
    __shared__ __align__(16) float gates_lds[8 * 256];    // 8 KB
    __shared__ __align__(16) float h_lds[8 * CH];
    __shared__ __align__(16) float c_lds[8 * CH];
    __shared__ int cidx_lds[8 * LC];
    __shared__ int len_lds[8];

    {
        float4* emb4 = reinterpret_cast<float4*>(emb_lds);
        #pragma unroll
        for (int i = 0; i < 8; ++i) {
            const int c = i * 256 + j;
            emb4[c] = ld4<BF>(char_emb, (size_t)c * 4);
        }
    }
    if (j < 128) cidx_lds[j] = char_idxs[w0 * LC + j];
    if (j < 8)   len_lds[j]  = char_lens[w0 + j];
    h_lds[j] = 0.f; h_lds[j + 256] = 0.f;
    c_lds[j] = 0.f; c_lds[j + 256] = 0.f;

    float4 wih4[16], whh4[16];
    #pragma unroll
    for (int kc = 0; kc < 16; ++kc) {
        wih4[kc] = ld4<BF>(Wih, (size_t)j * CE + kc * 4);
        whh4[kc] = ld4<BF>(Whh, (size_t)j * CH + kc * 4);
    }
    const float bias = ld1<BF>(bih, j) + ld1<BF>(bhh, j);
    __syncthreads();

    for (int t = 0; t < LC; ++t) {
        for (int w = 0; w < 8; ++w) {
            const int ci = cidx_lds[w * LC + t];
            const float4* x4  = reinterpret_cast<const float4*>(emb_lds + ci * CE);
            const float4* hh4 = reinterpret_cast<const float4*>(h_lds + w * CH);
            float a0 = 0.f, a1 = 0.f, a2 = 0.f, a3 = 0.f;
            #pragma unroll
            for (int kc = 0; kc < 16; ++kc) {
                const float4 xv = x4[kc]; const float4 hv = hh4[kc];
                const float4 wi = wih4[kc]; const float4 wh = whh4[kc];
                a0 = fmaf(wi.x, xv.x, a0); a1 = fmaf(wi.y, xv.y, a1);
                a2 = fmaf(wi.z, xv.z, a2); a3 = fmaf(wi.w, xv.w, a3);
                a0 = fmaf(wh.x, hv.x, a0); a1 = fmaf(wh.y, hv.y, a1);
                a2 = fmaf(wh.z, hv.z, a2); a3 = fmaf(wh.w, hv.w, a3);
            }
            gates_lds[w * 256 + j] = bias + ((a0 + a1) + (a2 + a3));
        }
        __syncthreads();
        #pragma unroll
        for (int rep = 0; rep < 2; ++rep) {
            const int p = j + rep * 256;       // p = w*64 + u
            const int w = p >> 6, u = p & 63;
            const float ig = gates_lds[w * 256 + u];
            const float fg = gates_lds[w * 256 + 64 + u];
            const float gg = gates_lds[w * 256 + 128 + u];
            const float og = gates_lds[w * 256 + 192 + u];
            const float cn = sigm(fg) * c_lds[p] + sigm(ig) * tanh_fast(gg);
            const float hn = sigm(og) * tanh_fast(cn);
            c_lds[p] = cn; h_lds[p] = hn;
            if (t == len_lds[w] - 1)
                cfeat[(size_t)(w0 + w) * CH + u] = hn;
        }
        __syncthreads();
    }
}

// ---------------------------------------------------------------------------
// Kernel B: Gx ring chunk. 16 words/block.
// ---------------------------------------------------------------------------
template <bool BF>
__global__ __launch_bounds__(256) void kgx(
        const u32* __restrict__ dtf,
        int t0, const int* __restrict__ word_idxs, const float* __restrict__ cfeat,
        const void* __restrict__ wemb, const void* __restrict__ Wih,
        const void* __restrict__ bih, const void* __restrict__ bhh,
        float* __restrict__ Gxr) {
    if ((*dtf != 0u) != BF) return;
    const int j = threadIdx.x;
    const int wr0 = blockIdx.x * 16;       // ring row base
    const int w0g = t0 + wr0;              // global word base
    __shared__ __align__(16) float wx[16 * 192];
    __shared__ int widx[16];
    if (j < 16) widx[j] = word_idxs[w0g + j];
    __syncthreads();
    {
        const int w = j >> 4, ch = j & 15;
        const size_t eb = (size_t)widx[w] * WE + ch * 8;
        const float4 f0 = ld4<BF>(wemb, eb), f1 = ld4<BF>(wemb, eb + 4);
        float4* dst = reinterpret_cast<float4*>(wx + w * 192 + ch * 8);
        dst[0] = f0; dst[1] = f1;
        const float4 cf = *reinterpret_cast<const float4*>(
            cfeat + (size_t)(w0g + w) * CH + ch * 4);
        *reinterpret_cast<float4*>(wx + w * 192 + WE + ch * 4) = cf;
    }
    __syncthreads();

    for (int g = 0; g < 4; ++g) {
        const int r = g * 256 + j;
        float acc[16];
        #pragma unroll
        for (int w = 0; w < 16; ++w) acc[w] = 0.f;
        #pragma unroll 8
        for (int kc = 0; kc < 48; ++kc) {
            const float4 wv = ld4<BF>(Wih, (size_t)r * 192 + kc * 4);
            #pragma unroll
            for (int w = 0; w < 16; ++w) {
                const float4 xv = *reinterpret_cast<const float4*>(wx + w * 192 + kc * 4);
                acc[w] = fmaf(wv.x, xv.x, acc[w]);
                acc[w] = fmaf(wv.y, xv.y, acc[w]);
                acc[w] = fmaf(wv.z, xv.z, acc[w]);
                acc[w] = fmaf(wv.w, xv.w, acc[w]);
            }
        }
        const float bias = ld1<BF>(bih, r) + ld1<BF>(bhh, r);
        #pragma unroll
        for (int w = 0; w < 16; ++w)
            Gxr[(size_t)(wr0 + w) * 1024 + r] = acc[w] + bias;
    }
}

// ---------------------------------------------------------------------------
// Kernel C: word LSTM steps [t0,t1). 4 blocks x 512 threads (8 waves).
// Block b owns units [64b,64b+64); wave w owns 8 of them (ubl = 8w+k).
// Lane l: row r=l&31 -> (unit k=r>>2, gate g=r&3), K-half kh=l>>5.
// Per step, each wave INDEPENDENTLY (no intra-block flags/partials):
//   1) each lane polls 4 tagged u64 h-packets (agent scope, 4 in flight),
//      packs f16x2 into the wave's private LDS slice (wave-local DS ops are
//      in-order -> no barrier);
//   2) 64 fdot2 over its K-half; shfl_xor(32) closes K; += Gx;
//   3) 3 shfls gather i,f,g,o; lanes g==0 do gate math; lane (g==0,kh==0)
//      publishes tagged packet for t+1 and records h in the LDS window.
// Tags are global step numbers; parity-2 slot reuse is safe by the
// consume-before-publish dependence chain. Gx / h-history live in 32-step
// LDS windows (2 barriers per window; vmcnt drains amortized 1/16 per step).
// ---------------------------------------------------------------------------
template <bool BF>
__global__ __launch_bounds__(512, 1) void kwlstm(
        const u32* __restrict__ dtf,
        int t0, int t1, const void* __restrict__ whh,
        const float* __restrict__ Gxr,
        float* __restrict__ hallr, u64* hgx2, float* csave) {
    if ((*dtf != 0u) != BF) return;
    const int j = threadIdx.x;
    const int b = blockIdx.x;
    const int w  = j >> 6;             // wave 0..7
    const int l  = j & 63;
    const int r  = l & 31;             // row-in-wave
    const int k  = r >> 2;             // unit-in-wave 0..7
    const int g  = r & 3;              // gate
    const int kh = l >> 5;             // K half
    const int ubl = 8 * w + k;         // block-local unit
    const int R = g * 256 + b * 64 + ubl;  // global gate row

    __shared__ __align__(16) u32 hpk[8][128];         // per-wave packed h (4 KB)
    __shared__ __align__(16) float gxw[WIN][4][64];   // Gx window (32 KB)
    __shared__ __align__(16) float hwin[WIN][64];     // h history (8 KB)

    h2 wv[64];                          // 128 f16 weights = 64 VGPRs
    #pragma unroll
    for (int kc = 0; kc < 32; ++kc) {
        const float4 f = ld4<BF>(whh, (size_t)R * 256 + kh * 128 + kc * 4);
        wv[2 * kc]     = __builtin_amdgcn_cvt_pkrtz(f.x, f.y);
        wv[2 * kc + 1] = __builtin_amdgcn_cvt_pkrtz(f.z, f.w);
    }
    float c_reg = 0.f;
    if (t0 > 0 && g == 0) c_reg = csave[b * 64 + ubl];

    for (int tw = t0; tw < t1; tw += WIN) {
        if (tw > t0) {
            __syncthreads();   // all waves done with previous window
            #pragma unroll
            for (int q = 0; q < 4; ++q) {   // flush h window (2048 f32)
                const int flat = j + q * 512;
                const int s = flat >> 6, u = flat & 63;
                hallr[(size_t)(tw - WIN - t0 + s) * 256 + b * 64 + u] = hwin[s][u];
            }
        }
        #pragma unroll
        for (int q = 0; q < 16; ++q) {      // stage Gx window (8192 f32)
            const int flat = j + q * 512;
            const int s = flat >> 8, rem = flat & 255;
            const int gg = rem >> 6, u = rem & 63;
            gxw[s][gg][u] =
                Gxr[(size_t)(tw - t0 + s) * 1024 + gg * 256 + b * 64 + u];
        }
        __syncthreads();

        for (int s = 0; s < WIN; ++s) {
            const int t = tw + s;
            const int par = t & 1;
            // ---- 1) gather h(t): 4 tagged packets per lane ----
            if (t == 0) {
                hpk[w][2 * l] = 0u; hpk[w][2 * l + 1] = 0u;
            } else {
                u64* bp = &hgx2[(size_t)par * 256 + 4 * l];
                const u32 tg = (u32)t;
                u64 v0, v1, v2, v3;
                for (;;) {
                    v0 = __hip_atomic_load(bp + 0, __ATOMIC_RELAXED, __HIP_MEMORY_SCOPE_AGENT);
                    v1 = __hip_atomic_load(bp + 1, __ATOMIC_RELAXED, __HIP_MEMORY_SCOPE_AGENT);
                    v2 = __hip_atomic_load(bp + 2, __ATOMIC_RELAXED, __HIP_MEMORY_SCOPE_AGENT);
                    v3 = __hip_atomic_load(bp + 3, __ATOMIC_RELAXED, __HIP_MEMORY_SCOPE_AGENT);
                    if (((u32)(v0 >> 32) == tg) & ((u32)(v1 >> 32) == tg) &
                        ((u32)(v2 >> 32) == tg) & ((u32)(v3 >> 32) == tg)) break;
                }
                h2u p0, p1;
                p0.h = __builtin_amdgcn_cvt_pkrtz(__uint_as_float((u32)v0),
                                                  __uint_as_float((u32)v1));
                p1.h = __builtin_amdgcn_cvt_pkrtz(__uint_as_float((u32)v2),
                                                  __uint_as_float((u32)v3));
                hpk[w][2 * l] = p0.u; hpk[w][2 * l + 1] = p1.u;
            }
            // ---- 2) matvec over this lane's K-half ----
            float acc = 0.f;
            const uint4* hq = reinterpret_cast<const uint4*>(&hpk[w][kh * 64]);
            #pragma unroll
            for (int i = 0; i < 16; ++i) {
                const uint4 q = hq[i];
                h2u x0, x1, x2, x3;
                x0.u = q.x; x1.u = q.y; x2.u = q.z; x3.u = q.w;
                acc = dot2f(wv[4 * i + 0], x0.h, acc);
                acc = dot2f(wv[4 * i + 1], x1.h, acc);
                acc = dot2f(wv[4 * i + 2], x2.h, acc);
                acc = dot2f(wv[4 * i + 3], x3.h, acc);
            }
            acc += __shfl_xor(acc, 32, 64);     // close K (both halves get sum)
            acc += gxw[s][g][ubl];
            // ---- 3) gather gates, gate math, publish ----
            const int base = l & ~3;
            const float gi = __shfl(acc, base + 0, 64);
            const float gf = __shfl(acc, base + 1, 64);
            const float gG = __shfl(acc, base + 2, 64);
            const float go = __shfl(acc, base + 3, 64);
            if (g == 0) {
                const float cn = sigm(gf) * c_reg + sigm(gi) * tanh_fast(gG);
                c_reg = cn;
                const float hn = sigm(go) * tanh_fast(cn);
                if (kh == 0) {
                    hwin[s][ubl] = hn;
                    const u64 pk = ((u64)(u32)(t + 1) << 32) | (u64)__float_as_uint(hn);
                    __hip_atomic_store(&hgx2[(size_t)((t + 1) & 1) * 256 + b * 64 + ubl],
                                       pk, __ATOMIC_RELAXED, __HIP_MEMORY_SCOPE_AGENT);
                }
            }
        }
    }
    __syncthreads();
    #pragma unroll
    for (int q = 0; q < 4; ++q) {   // final window flush
        const int flat = j + q * 512;
        const int s = flat >> 6, u = flat & 63;
        hallr[(size_t)(t1 - WIN - t0 + s) * 256 + b * 64 + u] = hwin[s][u];
    }
    if (g == 0 && kh == 0) csave[b * 64 + ubl] = c_reg;
}

// ---------------------------------------------------------------------------
// Kernel D: logits + log_softmax. One wave per word.
// ---------------------------------------------------------------------------
template <bool BF>
__global__ __launch_bounds__(64) void ktag(
        const u32* __restrict__ dtf,
        int t0, const float* __restrict__ hallr, const void* __restrict__ tagW,
        const void* __restrict__ tagb, void* __restrict__ out) {
    if ((*dtf != 0u) != BF) return;
    const int tr = blockIdx.x, j = threadIdx.x;
    const int t = t0 + tr;
    __shared__ __align__(16) float4 h4[64];
    h4[j] = reinterpret_cast<const float4*>(hallr + (size_t)tr * 256)[j];
    __syncthreads();
    float logit = -1e30f;
    if (j < NTAGS) {
        float a0 = 0.f, a1 = 0.f, a2 = 0.f, a3 = 0.f;
        #pragma unroll
        for (int kc = 0; kc < 64; ++kc) {
            const float4 wvv = ld4<BF>(tagW, (size_t)j * 256 + kc * 4);
            const float4 hv = h4[kc];
            a0 = fmaf(wvv.x, hv.x, a0); a1 = fmaf(wvv.y, hv.y, a1);
            a2 = fmaf(wvv.z, hv.z, a2); a3 = fmaf(wvv.w, hv.w, a3);
        }
        logit = ld1<BF>(tagb, j) + ((a0 + a1) + (a2 + a3));
    }
    float m = logit;
    #pragma unroll
    for (int off = 32; off >= 1; off >>= 1) m = fmaxf(m, __shfl_xor(m, off, 64));
    const float e = (j < NTAGS) ? __expf(logit - m) : 0.f;
    float ssum = e;
    #pragma unroll
    for (int off = 32; off >= 1; off >>= 1) ssum += __shfl_xor(ssum, off, 64);
    if (j < NTAGS)
        st1<BF>(out, (size_t)t * NTAGS + j, logit - m - __logf(ssum));
}

// ---------------------------------------------------------------------------
extern "C" void kernel_launch(void* const* d_in, const int* in_sizes, int n_in,
                              void* d_out, int out_size, void* d_ws, size_t ws_size,
                              hipStream_t stream) {
    const int*  word_idxs = (const int*)d_in[0];
    const int*  char_idxs = (const int*)d_in[1];
    const int*  char_lens = (const int*)d_in[2];
    const void* char_emb  = d_in[3];
    const void* char_Wih  = d_in[4];
    const void* char_Whh  = d_in[5];
    const void* char_bih  = d_in[6];
    const void* char_bhh  = d_in[7];
    const void* word_emb  = d_in[8];
    const void* word_Wih  = d_in[9];
    const void* word_Whh  = d_in[10];
    const void* word_bih  = d_in[11];
    const void* word_bhh  = d_in[12];
    const void* tag_W     = d_in[13];
    const void* tag_b     = d_in[14];

    // ws layout:
    //   [0,64)        dtflag u32
    //   [64,4160)     hgx2 u64[2][256]
    //   [4224,5248)   csave f32[256]
    //   [8192,+2MB)   cfeat f32[8192*64]
    //   [ring0,...)   Gx ring f32[CT*1024] + hall ring f32[CT*256]
    char* ws = (char*)d_ws;
    u32*   dtf    = (u32*)(ws);
    u64*   hgx2   = (u64*)(ws + 64);
    float* csave  = (float*)(ws + 4224);
    float* cfeat  = (float*)(ws + 8192);
    const size_t ring0 = 8192 + (size_t)S_LEN * CH * 4;

    int NC = 256;
    const int ncs[9] = {1, 2, 4, 8, 16, 32, 64, 128, 256};
    for (int i = 0; i < 9; ++i) {
        const int ct = S_LEN / ncs[i];
        if (ring0 + (size_t)ct * 5120 <= ws_size) { NC = ncs[i]; break; }
    }
    const int CT = S_LEN / NC;   // multiple of 32
    float* Gxr   = (float*)(ws + ring0);
    float* hallr = (float*)(ws + ring0 + (size_t)CT * 4096);

    hipLaunchKernelGGL(kdetect, dim3(1), dim3(64), 0, stream, char_emb, dtf);
    hipLaunchKernelGGL(kchar<true>,  dim3(S_LEN / 8), dim3(256), 0, stream,
                       dtf, char_idxs, char_lens, char_emb, char_Wih, char_Whh,
                       char_bih, char_bhh, cfeat);
    hipLaunchKernelGGL(kchar<false>, dim3(S_LEN / 8), dim3(256), 0, stream,
                       dtf, char_idxs, char_lens, char_emb, char_Wih, char_Whh,
                       char_bih, char_bhh, cfeat);
    for (int c = 0; c < NC; ++c) {
        const int t0 = c * CT;
        hipLaunchKernelGGL(kgx<true>,  dim3(CT / 16), dim3(256), 0, stream,
                           dtf, t0, word_idxs, cfeat, word_emb, word_Wih,
                           word_bih, word_bhh, Gxr);
        hipLaunchKernelGGL(kgx<false>, dim3(CT / 16), dim3(256), 0, stream,
                           dtf, t0, word_idxs, cfeat, word_emb, word_Wih,
                           word_bih, word_bhh, Gxr);
        hipLaunchKernelGGL(kwlstm<true>,  dim3(4), dim3(512), 0, stream,
                           dtf, t0, t0 + CT, word_Whh, Gxr, hallr, hgx2, csave);
        hipLaunchKernelGGL(kwlstm<false>, dim3(4), dim3(512), 0, stream,
                           dtf, t0, t0 + CT, word_Whh, Gxr, hallr, hgx2, csave);
        hipLaunchKernelGGL(ktag<true>,  dim3(CT), dim3(64), 0, stream,
                           dtf, t0, hallr, tag_W, tag_b, d_out);
        hipLaunchKernelGGL(ktag<false>, dim3(CT), dim3(64), 0, stream,
                           dtf, t0, hallr, tag_W, tag_b, d_out);
    }
}

// Round 11
// 16456.259 us; speedup vs baseline: 1.2047x; 1.2047x over previous
//
#include <hip/hip_runtime.h>
#include <hip/hip_bf16.h>

#define S_LEN 8192
#define LC 16
#define CE 64
#define CH 64
#define WE 128
#define NTAGS 50
#define WIN 32

using bf16 = __hip_bfloat16;
typedef unsigned int u32;
typedef unsigned long long u64;
typedef __fp16 h2 __attribute__((ext_vector_type(2)));   // matches pkrtz/fdot2
union h2u { h2 h; u32 u; };

__device__ __forceinline__ float bfbits2f(unsigned short u) {
    union { unsigned int i; float f; } v; v.i = ((unsigned int)u) << 16; return v.f;
}
__device__ __forceinline__ float sigm(float x) {
    return __builtin_amdgcn_rcpf(1.0f + __expf(-x));
}
__device__ __forceinline__ float tanh_fast(float x) {
    return 1.0f - 2.0f * __builtin_amdgcn_rcpf(__expf(2.0f * x) + 1.0f);
}
__device__ __forceinline__ float dot2f(h2 a, h2 b, float c) {
#if __has_builtin(__builtin_amdgcn_fdot2)
    return __builtin_amdgcn_fdot2(a, b, c, false);
#else
    return fmaf((float)a.x, (float)b.x, fmaf((float)a.y, (float)b.y, c));
#endif
}

// dtype-generic accessors ----------------------------------------------------
template <bool BF>
__device__ __forceinline__ float ld1(const void* p, size_t i) {
    if constexpr (BF) return bfbits2f(((const unsigned short*)p)[i]);
    else              return ((const float*)p)[i];
}
template <bool BF>
__device__ __forceinline__ float4 ld4(const void* p, size_t i) {  // elems i..i+3
    if constexpr (BF) {
        const ushort4 s = *reinterpret_cast<const ushort4*>((const unsigned short*)p + i);
        return make_float4(bfbits2f(s.x), bfbits2f(s.y), bfbits2f(s.z), bfbits2f(s.w));
    } else {
        return *reinterpret_cast<const float4*>((const float*)p + i);
    }
}
template <bool BF>
__device__ __forceinline__ void st1(void* p, size_t i, float v) {
    if constexpr (BF) ((bf16*)p)[i] = __float2bfloat16(v);
    else              ((float*)p)[i] = v;
}

// ---------------------------------------------------------------------------
// Detector: classify float-tensor dtype from char_emb's first 256 ushorts.
// ---------------------------------------------------------------------------
__global__ void kdetect(const void* emb, u32* flag) {
    const int j = threadIdx.x;           // 64 lanes
    int s = 0;
    #pragma unroll
    for (int k = 0; k < 4; ++k) {
        const unsigned short u = ((const unsigned short*)emb)[j * 4 + k];
        const int e = (u >> 7) & 0xFF;
        s += (e >= 100 && e <= 133) ? 1 : 0;
    }
    #pragma unroll
    for (int off = 32; off >= 1; off >>= 1) s += __shfl_xor(s, off, 64);
    if (j == 0) *flag = (s >= 200) ? 1u : 0u;
}

// ---------------------------------------------------------------------------
// Kernel A: char LSTM. 8 words/block, 256 threads (thread j = gate row j).
// ---------------------------------------------------------------------------
template <bool BF>
__global__ __launch_bounds__(256, 2) void kchar(
        const u32* __restrict__ dtf,
        const int* __restrict__ char_idxs, const int* __restrict__ char_lens,
        const void* __restrict__ char_emb,
        const void* __restrict__ Wih, const void* __restrict__ Whh,
        const void* __restrict__ bih, const void* __restrict__ bhh,
        float* __restrict__ cfeat) {
    if ((*dtf != 0u) != BF) return;
    const int j = threadIdx.x;
    const int w0 = blockIdx.x * 8;

    __shared__ __align__(16) float emb_lds[128 * CE];     // 32 KB
    __shared__ __align__(16) float gates_lds[8 * 256];    // 8 KB
    __shared__ __align__(16) float h_lds[8 * CH];
    __shared__ __align__(16) float c_lds[8 * CH];
    __shared__ int cidx_lds[8 * LC];
    __shared__ int len_lds[8];

    {
        float4* emb4 = reinterpret_cast<float4*>(emb_lds);
        #pragma unroll
        for (int i = 0; i < 8; ++i) {
            const int c = i * 256 + j;
            emb4[c] = ld4<BF>(char_emb, (size_t)c * 4);
        }
    }
    if (j < 128) cidx_lds[j] = char_idxs[w0 * LC + j];
    if (j < 8)   len_lds[j]  = char_lens[w0 + j];
    h_lds[j] = 0.f; h_lds[j + 256] = 0.f;
    c_lds[j] = 0.f; c_lds[j + 256] = 0.f;

    float4 wih4[16], whh4[16];
    #pragma unroll
    for (int kc = 0; kc < 16; ++kc) {
        wih4[kc] = ld4<BF>(Wih, (size_t)j * CE + kc * 4);
        whh4[kc] = ld4<BF>(Whh, (size_t)j * CH + kc * 4);
    }
    const float bias = ld1<BF>(bih, j) + ld1<BF>(bhh, j);
    __syncthreads();

    for (int t = 0; t < LC; ++t) {
        for (int w = 0; w < 8; ++w) {
            const int ci = cidx_lds[w * LC + t];
            const float4* x4  = reinterpret_cast<const float4*>(emb_lds + ci * CE);
            const float4* hh4 = reinterpret_cast<const float4*>(h_lds + w * CH);
            float a0 = 0.f, a1 = 0.f, a2 = 0.f, a3 = 0.f;
            #pragma unroll
            for (int kc = 0; kc < 16; ++kc) {
                const float4 xv = x4[kc]; const float4 hv = hh4[kc];
                const float4 wi = wih4[kc]; const float4 wh = whh4[kc];
                a0 = fmaf(wi.x, xv.x, a0); a1 = fmaf(wi.y, xv.y, a1);
                a2 = fmaf(wi.z, xv.z, a2); a3 = fmaf(wi.w, xv.w, a3);
                a0 = fmaf(wh.x, hv.x, a0); a1 = fmaf(wh.y, hv.y, a1);
                a2 = fmaf(wh.z, hv.z, a2); a3 = fmaf(wh.w, hv.w, a3);
            }
            gates_lds[w * 256 + j] = bias + ((a0 + a1) + (a2 + a3));
        }
        __syncthreads();
        #pragma unroll
        for (int rep = 0; rep < 2; ++rep) {
            const int p = j + rep * 256;       // p = w*64 + u
            const int w = p >> 6, u = p & 63;
            const float ig = gates_lds[w * 256 + u];
            const float fg = gates_lds[w * 256 + 64 + u];
            const float gg = gates_lds[w * 256 + 128 + u];
            const float og = gates_lds[w * 256 + 192 + u];
            const float cn = sigm(fg) * c_lds[p] + sigm(ig) * tanh_fast(gg);
            const float hn = sigm(og) * tanh_fast(cn);
            c_lds[p] = cn; h_lds[p] = hn;
            if (t == len_lds[w] - 1)
                cfeat[(size_t)(w0 + w) * CH + u] = hn;
        }
        __syncthreads();
    }
}

// ---------------------------------------------------------------------------
// Kernel B: Gx ring chunk. 16 words/block.
// ---------------------------------------------------------------------------
template <bool BF>
__global__ __launch_bounds__(256) void kgx(
        const u32* __restrict__ dtf,
        int t0, const int* __restrict__ word_idxs, const float* __restrict__ cfeat,
        const void* __restrict__ wemb, const void* __restrict__ Wih,
        const void* __restrict__ bih, const void* __restrict__ bhh,
        float* __restrict__ Gxr) {
    if ((*dtf != 0u) != BF) return;
    const int j = threadIdx.x;
    const int wr0 = blockIdx.x * 16;       // ring row base
    const int w0g = t0 + wr0;              // global word base
    __shared__ __align__(16) float wx[16 * 192];
    __shared__ int widx[16];
    if (j < 16) widx[j] = word_idxs[w0g + j];
    __syncthreads();
    {
        const int w = j >> 4, ch = j & 15;
        const size_t eb = (size_t)widx[w] * WE + ch * 8;
        const float4 f0 = ld4<BF>(wemb, eb), f1 = ld4<BF>(wemb, eb + 4);
        float4* dst = reinterpret_cast<float4*>(wx + w * 192 + ch * 8);
        dst[0] = f0; dst[1] = f1;
        const float4 cf = *reinterpret_cast<const float4*>(
            cfeat + (size_t)(w0g + w) * CH + ch * 4);
        *reinterpret_cast<float4*>(wx + w * 192 + WE + ch * 4) = cf;
    }
    __syncthreads();

    for (int g = 0; g < 4; ++g) {
        const int r = g * 256 + j;
        float acc[16];
        #pragma unroll
        for (int w = 0; w < 16; ++w) acc[w] = 0.f;
        #pragma unroll 8
        for (int kc = 0; kc < 48; ++kc) {
            const float4 wv = ld4<BF>(Wih, (size_t)r * 192 + kc * 4);
            #pragma unroll
            for (int w = 0; w < 16; ++w) {
                const float4 xv = *reinterpret_cast<const float4*>(wx + w * 192 + kc * 4);
                acc[w] = fmaf(wv.x, xv.x, acc[w]);
                acc[w] = fmaf(wv.y, xv.y, acc[w]);
                acc[w] = fmaf(wv.z, xv.z, acc[w]);
                acc[w] = fmaf(wv.w, xv.w, acc[w]);
            }
        }
        const float bias = ld1<BF>(bih, r) + ld1<BF>(bhh, r);
        #pragma unroll
        for (int w = 0; w < 16; ++w)
            Gxr[(size_t)(wr0 + w) * 1024 + r] = acc[w] + bias;
    }
}

// ---------------------------------------------------------------------------
// Kernel C: word LSTM steps [t0,t1). 4 blocks x 256 threads (4 waves,
// 1 wave/SIMD, 256-VGPR budget). Block b owns units [64b,64b+64).
// Lane j = gate-row: gate g=j>>6, unit u=j&63; holds the FULL K=256 row as
// 128 packed-f16 pairs (128 VGPRs, resident).
// Exchange: 128 u64 packets total, each (tag<<32)|f16x2 covering a UNIT PAIR.
// Per step: lanes 64..159 (waves 1,2) poll the 96 REMOTE pairs (single load
// per spin iteration -> minimum L3 contention) and drop the packed u32
// straight into hpk[par]; barrier X; all 256 lanes matvec (32 broadcast
// ds_read_b128 + 128 fdot2) + Gx from the LDS window; barrier Y; wave 0
// does gate math, writes h to the window, packs own pairs into hpk[par^1]
// and publishes 32 tagged packets (overlapped with next step's polling by
// waves 1,2). Parity-2 slot reuse safe by the consume-before-publish chain.
// Gx/h history in 32-step LDS windows (2 extra barriers per window).
// ---------------------------------------------------------------------------
template <bool BF>
__global__ __launch_bounds__(256, 1) void kwlstm(
        const u32* __restrict__ dtf,
        int t0, int t1, const void* __restrict__ whh,
        const float* __restrict__ Gxr,
        float* __restrict__ hallr, u64* hgx2, float* csave) {
    if ((*dtf != 0u) != BF) return;
    const int j = threadIdx.x;
    const int b = blockIdx.x;
    const int g = j >> 6, u = j & 63;
    const int R = g * 256 + b * 64 + u;    // global gate-row

    __shared__ __align__(16) u32 hpk[2][128];      // packed f16x2 h (1 KB)
    __shared__ __align__(16) float gat[256];       // gate pre-activations
    __shared__ __align__(16) float gxw[WIN][256];  // Gx window (32 KB)
    __shared__ __align__(16) float hwin[WIN][64];  // h history window (8 KB)

    h2 wv[128];                          // 256 f16 weights = 128 VGPRs
    #pragma unroll
    for (int kc = 0; kc < 64; ++kc) {
        const float4 f = ld4<BF>(whh, (size_t)R * 256 + kc * 4);
        wv[2 * kc]     = __builtin_amdgcn_cvt_pkrtz(f.x, f.y);
        wv[2 * kc + 1] = __builtin_amdgcn_cvt_pkrtz(f.z, f.w);
    }
    // poll duty: lanes 64..159 handle the 96 remote pairs
    const int pi = j - 64;
    const int pp = (pi >= 0 && pi < 96) ? (pi + (pi >= 32 * b ? 32 : 0)) : -1;

    float c_reg = 0.f;
    if (t0 > 0 && j < 64) c_reg = csave[b * 64 + j];
    if (j < 128) hpk[0][j] = 0u;          // h(0) = 0 packed

    for (int tw = t0; tw < t1; tw += WIN) {
        if (tw > t0) {
            __syncthreads();              // wave0 finished previous window
            #pragma unroll
            for (int q = 0; q < 8; ++q) { // flush h window (2048 f32)
                const int flat = j + q * 256;
                const int s = flat >> 6, uu = flat & 63;
                hallr[(size_t)(tw - WIN - t0 + s) * 256 + b * 64 + uu] = hwin[s][uu];
            }
        }
        #pragma unroll
        for (int q = 0; q < 8; ++q) {     // stage Gx window (2048 float4)
            const int qi = j + q * 256;
            const int s = qi >> 6, quad = qi & 63;
            const int gg = quad >> 4, off = (quad & 15) * 4;
            *reinterpret_cast<float4*>(&gxw[s][gg * 64 + off]) =
                *reinterpret_cast<const float4*>(
                    &Gxr[(size_t)(tw - t0 + s) * 1024 + gg * 256 + b * 64 + off]);
        }
        __syncthreads();

        for (int s = 0; s < WIN; ++s) {
            const int t = tw + s;
            const int par = t & 1;
            // ---- phase 1: poll remote pairs ----
            if (t > 0) {
                const u32 tg = (u32)t;
                if (t == t0) {            // chunk start: cover ALL pairs
                    if (j < 128) {
                        u64 pk;
                        do {
                            pk = __hip_atomic_load(&hgx2[(size_t)par * 128 + j],
                                                   __ATOMIC_RELAXED, __HIP_MEMORY_SCOPE_AGENT);
                        } while ((u32)(pk >> 32) != tg);
                        hpk[par][j] = (u32)pk;
                    }
                } else if (pp >= 0) {
                    u64 pk;
                    do {
                        pk = __hip_atomic_load(&hgx2[(size_t)par * 128 + pp],
                                               __ATOMIC_RELAXED, __HIP_MEMORY_SCOPE_AGENT);
                    } while ((u32)(pk >> 32) != tg);
                    hpk[par][pp] = (u32)pk;
                }
            }
            __syncthreads();              // X: hpk[par] complete
            // ---- phase 2: matvec (broadcast LDS reads + fdot2) ----
            float acc = 0.f;
            const uint4* hq = reinterpret_cast<const uint4*>(&hpk[par][0]);
            #pragma unroll
            for (int i = 0; i < 32; ++i) {
                const uint4 q = hq[i];
                h2u x0, x1, x2, x3;
                x0.u = q.x; x1.u = q.y; x2.u = q.z; x3.u = q.w;
                acc = dot2f(wv[4 * i + 0], x0.h, acc);
                acc = dot2f(wv[4 * i + 1], x1.h, acc);
                acc = dot2f(wv[4 * i + 2], x2.h, acc);
                acc = dot2f(wv[4 * i + 3], x3.h, acc);
            }
            gat[j] = acc + gxw[s][j];
            __syncthreads();              // Y: gates ready
            // ---- phase 3: wave 0 gate math + publish ----
            if (j < 64) {
                const float gi = gat[j],        gf = gat[64 + j];
                const float gG = gat[128 + j],  go = gat[192 + j];
                const float cn = sigm(gf) * c_reg + sigm(gi) * tanh_fast(gG);
                c_reg = cn;
                const float hn = sigm(go) * tanh_fast(cn);
                hwin[s][j] = hn;
                const float ho = __shfl_xor(hn, 1, 64);
                if ((j & 1) == 0) {
                    h2u pq; pq.h = __builtin_amdgcn_cvt_pkrtz(hn, ho);
                    const int p = 32 * b + (j >> 1);
                    hpk[par ^ 1][p] = pq.u;
                    const u64 pk = ((u64)(u32)(t + 1) << 32) | (u64)pq.u;
                    __hip_atomic_store(&hgx2[(size_t)(par ^ 1) * 128 + p], pk,
                                       __ATOMIC_RELAXED, __HIP_MEMORY_SCOPE_AGENT);
                }
            }
        }
    }
    __syncthreads();
    #pragma unroll
    for (int q = 0; q < 8; ++q) {         // final window flush
        const int flat = j + q * 256;
        const int s = flat >> 6, uu = flat & 63;
        hallr[(size_t)(t1 - WIN - t0 + s) * 256 + b * 64 + uu] = hwin[s][uu];
    }
    if (j < 64) csave[b * 64 + j] = c_reg;
}

// ---------------------------------------------------------------------------
// Kernel D: logits + log_softmax. One wave per word.
// ---------------------------------------------------------------------------
template <bool BF>
__global__ __launch_bounds__(64) void ktag(
        const u32* __restrict__ dtf,
        int t0, const float* __restrict__ hallr, const void* __restrict__ tagW,
        const void* __restrict__ tagb, void* __restrict__ out) {
    if ((*dtf != 0u) != BF) return;
    const int tr = blockIdx.x, j = threadIdx.x;
    const int t = t0 + tr;
    __shared__ __align__(16) float4 h4[64];
    h4[j] = reinterpret_cast<const float4*>(hallr + (size_t)tr * 256)[j];
    __syncthreads();
    float logit = -1e30f;
    if (j < NTAGS) {
        float a0 = 0.f, a1 = 0.f, a2 = 0.f, a3 = 0.f;
        #pragma unroll
        for (int kc = 0; kc < 64; ++kc) {
            const float4 wvv = ld4<BF>(tagW, (size_t)j * 256 + kc * 4);
            const float4 hv = h4[kc];
            a0 = fmaf(wvv.x, hv.x, a0); a1 = fmaf(wvv.y, hv.y, a1);
            a2 = fmaf(wvv.z, hv.z, a2); a3 = fmaf(wvv.w, hv.w, a3);
        }
        logit = ld1<BF>(tagb, j) + ((a0 + a1) + (a2 + a3));
    }
    float m = logit;
    #pragma unroll
    for (int off = 32; off >= 1; off >>= 1) m = fmaxf(m, __shfl_xor(m, off, 64));
    const float e = (j < NTAGS) ? __expf(logit - m) : 0.f;
    float ssum = e;
    #pragma unroll
    for (int off = 32; off >= 1; off >>= 1) ssum += __shfl_xor(ssum, off, 64);
    if (j < NTAGS)
        st1<BF>(out, (size_t)t * NTAGS + j, logit - m - __logf(ssum));
}

// ---------------------------------------------------------------------------
extern "C" void kernel_launch(void* const* d_in, const int* in_sizes, int n_in,
                              void* d_out, int out_size, void* d_ws, size_t ws_size,
                              hipStream_t stream) {
    const int*  word_idxs = (const int*)d_in[0];
    const int*  char_idxs = (const int*)d_in[1];
    const int*  char_lens = (const int*)d_in[2];
    const void* char_emb  = d_in[3];
    const void* char_Wih  = d_in[4];
    const void* char_Whh  = d_in[5];
    const void* char_bih  = d_in[6];
    const void* char_bhh  = d_in[7];
    const void* word_emb  = d_in[8];
    const void* word_Wih  = d_in[9];
    const void* word_Whh  = d_in[10];
    const void* word_bih  = d_in[11];
    const void* word_bhh  = d_in[12];
    const void* tag_W     = d_in[13];
    const void* tag_b     = d_in[14];

    // ws layout:
    //   [0,64)        dtflag u32
    //   [64,2112)     hgx2 u64[2][128]
    //   [4224,5248)   csave f32[256]
    //   [8192,+2MB)   cfeat f32[8192*64]
    //   [ring0,...)   Gx ring f32[CT*1024] + hall ring f32[CT*256]
    char* ws = (char*)d_ws;
    u32*   dtf    = (u32*)(ws);
    u64*   hgx2   = (u64*)(ws + 64);
    float* csave  = (float*)(ws + 4224);
    float* cfeat  = (float*)(ws + 8192);
    const size_t ring0 = 8192 + (size_t)S_LEN * CH * 4;

    int NC = 256;
    const int ncs[9] = {1, 2, 4, 8, 16, 32, 64, 128, 256};
    for (int i = 0; i < 9; ++i) {
        const int ct = S_LEN / ncs[i];
        if (ring0 + (size_t)ct * 5120 <= ws_size) { NC = ncs[i]; break; }
    }
    const int CT = S_LEN / NC;   // multiple of 32
    float* Gxr   = (float*)(ws + ring0);
    float* hallr = (float*)(ws + ring0 + (size_t)CT * 4096);

    hipLaunchKernelGGL(kdetect, dim3(1), dim3(64), 0, stream, char_emb, dtf);
    hipLaunchKernelGGL(kchar<true>,  dim3(S_LEN / 8), dim3(256), 0, stream,
                       dtf, char_idxs, char_lens, char_emb, char_Wih, char_Whh,
                       char_bih, char_bhh, cfeat);
    hipLaunchKernelGGL(kchar<false>, dim3(S_LEN / 8), dim3(256), 0, stream,
                       dtf, char_idxs, char_lens, char_emb, char_Wih, char_Whh,
                       char_bih, char_bhh, cfeat);
    for (int c = 0; c < NC; ++c) {
        const int t0 = c * CT;
        hipLaunchKernelGGL(kgx<true>,  dim3(CT / 16), dim3(256), 0, stream,
                           dtf, t0, word_idxs, cfeat, word_emb, word_Wih,
                           word_bih, word_bhh, Gxr);
        hipLaunchKernelGGL(kgx<false>, dim3(CT / 16), dim3(256), 0, stream,
                           dtf, t0, word_idxs, cfeat, word_emb, word_Wih,
                           word_bih, word_bhh, Gxr);
        hipLaunchKernelGGL(kwlstm<true>,  dim3(4), dim3(256), 0, stream,
                           dtf, t0, t0 + CT, word_Whh, Gxr, hallr, hgx2, csave);
        hipLaunchKernelGGL(kwlstm<false>, dim3(4), dim3(256), 0, stream,
                           dtf, t0, t0 + CT, word_Whh, Gxr, hallr, hgx2, csave);
        hipLaunchKernelGGL(ktag<true>,  dim3(CT), dim3(64), 0, stream,
                           dtf, t0, hallr, tag_W, tag_b, d_out);
        hipLaunchKernelGGL(ktag<false>, dim3(CT), dim3(64), 0, stream,
                           dtf, t0, hallr, tag_W, tag_b, d_out);
    }
}